// Round 1
// baseline (56.365 us; speedup 1.0000x reference)
//
#include <hip/hip_runtime.h>

// ---------------------------------------------------------------------------
// Kernel 1: forward kinematics + sphere transform.
// One thread per batch. Serial walk over 16 joints.
// Writes world-frame spheres as float4 (x,y,z,r) to ws[batch*128 + l*8 + s].
// ---------------------------------------------------------------------------
__global__ __launch_bounds__(256) void fk_kernel(
    const float* __restrict__ q,        // [B,16]
    const float* __restrict__ frot,     // [16,3,3]
    const float* __restrict__ ftrans,   // [16,3]
    const float* __restrict__ axes,     // [16,3]
    const float* __restrict__ spheres,  // [16,8,4]
    float4* __restrict__ ws,            // [chunk,128]
    int base, int chunk)
{
    int idx = blockIdx.x * blockDim.x + threadIdx.x;
    if (idx >= chunk) return;
    int b = base + idx;

    float R00=1.f,R01=0.f,R02=0.f;
    float R10=0.f,R11=1.f,R12=0.f;
    float R20=0.f,R21=0.f,R22=1.f;
    float t0=0.f,t1=0.f,t2=0.f;

    for (int l = 0; l < 16; ++l) {
        float qv = q[b*16 + l];

        // t = t + R_parent @ ftrans   (uses parent R, before R update)
        float f0 = ftrans[3*l+0], f1 = ftrans[3*l+1], f2 = ftrans[3*l+2];
        t0 = fmaf(R00,f0, fmaf(R01,f1, fmaf(R02,f2, t0)));
        t1 = fmaf(R10,f0, fmaf(R11,f1, fmaf(R12,f2, t1)));
        t2 = fmaf(R20,f0, fmaf(R21,f1, fmaf(R22,f2, t2)));

        // A = R_parent @ F
        float F00=frot[9*l+0],F01=frot[9*l+1],F02=frot[9*l+2];
        float F10=frot[9*l+3],F11=frot[9*l+4],F12=frot[9*l+5];
        float F20=frot[9*l+6],F21=frot[9*l+7],F22=frot[9*l+8];
        float A00 = fmaf(R00,F00, fmaf(R01,F10, R02*F20));
        float A01 = fmaf(R00,F01, fmaf(R01,F11, R02*F21));
        float A02 = fmaf(R00,F02, fmaf(R01,F12, R02*F22));
        float A10 = fmaf(R10,F00, fmaf(R11,F10, R12*F20));
        float A11 = fmaf(R10,F01, fmaf(R11,F11, R12*F21));
        float A12 = fmaf(R10,F02, fmaf(R11,F12, R12*F22));
        float A20 = fmaf(R20,F00, fmaf(R21,F10, R22*F20));
        float A21 = fmaf(R20,F01, fmaf(R21,F11, R22*F21));
        float A22 = fmaf(R20,F02, fmaf(R21,F12, R22*F22));

        // R = A @ Rodrigues(axis, qv) = A + s*(A K) + (1-c)*(A K K)
        // (A K) row r = cross(A_r, axis); (A K K) row r = cross((A K)_r, axis)
        float ax = axes[3*l+0], ay = axes[3*l+1], az = axes[3*l+2];
        float s = sinf(qv), c = cosf(qv);
        float oc = 1.0f - c;

        float u0 = fmaf(A01,az, -A02*ay);
        float u1 = fmaf(A02,ax, -A00*az);
        float u2 = fmaf(A00,ay, -A01*ax);
        float v0 = fmaf(u1,az, -u2*ay);
        float v1 = fmaf(u2,ax, -u0*az);
        float v2 = fmaf(u0,ay, -u1*ax);
        R00 = fmaf(oc,v0, fmaf(s,u0, A00));
        R01 = fmaf(oc,v1, fmaf(s,u1, A01));
        R02 = fmaf(oc,v2, fmaf(s,u2, A02));

        u0 = fmaf(A11,az, -A12*ay);
        u1 = fmaf(A12,ax, -A10*az);
        u2 = fmaf(A10,ay, -A11*ax);
        v0 = fmaf(u1,az, -u2*ay);
        v1 = fmaf(u2,ax, -u0*az);
        v2 = fmaf(u0,ay, -u1*ax);
        R10 = fmaf(oc,v0, fmaf(s,u0, A10));
        R11 = fmaf(oc,v1, fmaf(s,u1, A11));
        R12 = fmaf(oc,v2, fmaf(s,u2, A12));

        u0 = fmaf(A21,az, -A22*ay);
        u1 = fmaf(A22,ax, -A20*az);
        u2 = fmaf(A20,ay, -A21*ax);
        v0 = fmaf(u1,az, -u2*ay);
        v1 = fmaf(u2,ax, -u0*az);
        v2 = fmaf(u0,ay, -u1*ax);
        R20 = fmaf(oc,v0, fmaf(s,u0, A20));
        R21 = fmaf(oc,v1, fmaf(s,u1, A21));
        R22 = fmaf(oc,v2, fmaf(s,u2, A22));

        // world spheres for this link
        #pragma unroll
        for (int sp = 0; sp < 8; ++sp) {
            float4 cs = reinterpret_cast<const float4*>(spheres)[l*8 + sp];
            float wx = fmaf(R00,cs.x, fmaf(R01,cs.y, fmaf(R02,cs.z, t0)));
            float wy = fmaf(R10,cs.x, fmaf(R11,cs.y, fmaf(R12,cs.z, t1)));
            float wz = fmaf(R20,cs.x, fmaf(R21,cs.y, fmaf(R22,cs.z, t2)));
            ws[(size_t)idx*128 + l*8 + sp] = make_float4(wx, wy, wz, cs.w);
        }
    }
}

// ---------------------------------------------------------------------------
// Kernel 2: pairwise sphere penetration + per-link max.
// One wave (64 lanes) per batch, 4 batches per 256-thread block.
// Lane l owns sphere pair (row sphere l>>3, col sphere l&7) of each link pair.
// Only link pairs with j >= i+2 are computed (mask |i-j|>1, symmetric).
// m[] init to -100 reproduces the reference's masked fill value.
// ---------------------------------------------------------------------------
__global__ __launch_bounds__(256) void pair_kernel(
    const float4* __restrict__ ws,   // [chunk,128]
    float* __restrict__ out,         // [B,16]
    int base, int chunk)
{
    __shared__ float4 sph[4*128];
    int t = threadIdx.x;

    // cooperative staging: 512 float4 per block, fully coalesced
    int g = blockIdx.x*512 + t;
    int tot = chunk*128;
    if (g < tot)       sph[t]       = ws[g];
    if (g + 256 < tot) sph[t + 256] = ws[g + 256];
    __syncthreads();

    int w = t >> 6;
    int lane = t & 63;
    int bi = blockIdx.x*4 + w;
    if (bi >= chunk) return;
    int b = base + bi;

    const float4* S = &sph[w*128];
    int sr = lane >> 3;   // row sphere index
    int sc = lane & 7;    // col sphere index

    // cache this lane's column sphere of every link in registers
    float4 cs[16];
    #pragma unroll
    for (int j = 0; j < 16; ++j) cs[j] = S[j*8 + sc];

    float m[16];
    #pragma unroll
    for (int k = 0; k < 16; ++k) m[k] = -100.0f;

    #pragma unroll
    for (int i = 0; i < 14; ++i) {
        float4 rs = S[i*8 + sr];
        #pragma unroll
        for (int j = i + 2; j < 16; ++j) {
            float dx = rs.x - cs[j].x;
            float dy = rs.y - cs[j].y;
            float dz = rs.z - cs[j].z;
            float d2 = fmaf(dx,dx, fmaf(dy,dy, dz*dz));
            d2 = fmaxf(d2, 1e-12f);
            float pen = rs.w + cs[j].w - __builtin_amdgcn_sqrtf(d2);
            m[i] = fmaxf(m[i], pen);
            m[j] = fmaxf(m[j], pen);
        }
    }

    // wave-wide max for each link (butterfly leaves result in all lanes)
    #pragma unroll
    for (int k = 0; k < 16; ++k) {
        float v = m[k];
        #pragma unroll
        for (int off = 32; off > 0; off >>= 1)
            v = fmaxf(v, __shfl_xor(v, off, 64));
        m[k] = v;
    }

    if (lane == 0) {
        #pragma unroll
        for (int k = 0; k < 16; ++k) out[(size_t)b*16 + k] = m[k];
    }
}

// ---------------------------------------------------------------------------
extern "C" void kernel_launch(void* const* d_in, const int* in_sizes, int n_in,
                              void* d_out, int out_size, void* d_ws, size_t ws_size,
                              hipStream_t stream) {
    const float* q      = (const float*)d_in[0];
    const float* frot   = (const float*)d_in[1];
    const float* ftrans = (const float*)d_in[2];
    const float* axes   = (const float*)d_in[3];
    const float* sphere = (const float*)d_in[4];
    // d_in[5] (collision_mask) is deterministically |i-j|>1 -> computed inline.
    float* out = (float*)d_out;

    const int B = in_sizes[0] / 16;
    const size_t perBatch = 128 * sizeof(float4);   // 2 KB
    long long maxChunk = (long long)(ws_size / perBatch);
    if (maxChunk > B) maxChunk = B;
    if (maxChunk < 4) maxChunk = 4;   // ws_size is expected to be >= 8 KB

    for (int base = 0; base < B; ) {
        int chunk = (int)(((long long)(B - base) < maxChunk) ? (B - base) : maxChunk);
        fk_kernel<<<dim3((chunk + 255) / 256), dim3(256), 0, stream>>>(
            q, frot, ftrans, axes, sphere, (float4*)d_ws, base, chunk);
        pair_kernel<<<dim3((chunk + 3) / 4), dim3(256), 0, stream>>>(
            (const float4*)d_ws, out, base, chunk);
        base += chunk;
    }
}

// Round 2
// 33.726 us; speedup vs baseline: 1.6712x; 1.6712x over previous
//
#include <hip/hip_runtime.h>

// ---------------------------------------------------------------------------
// Fully fused: FK (parallel prefix over joints) + sphere transform + pairwise
// penetration + per-link max, one wave (64 lanes) per batch element.
//
// FK: link l's local transform M_l = [F_l * J_l(q_l) | f_l] as a 3x4
// homogeneous matrix; world pose T_l = M_0 * M_1 * ... * M_l computed with a
// 4-step Kogge-Stone inclusive scan across 16 lanes (shfl_up, width 16).
// All four 16-lane groups of the wave compute the same scan (lockstep-free);
// the 64 lanes then transform 128 spheres (2 each) into LDS.
//
// Pair phase: lane = (row sphere sr = lane>>3, col sphere sc = lane&7).
// Link pairs j >= i+2 only (collision_mask == |i-j|>1, symmetric); m[] init
// -100 reproduces the reference's masked fill.
// ---------------------------------------------------------------------------
__global__ __launch_bounds__(256) void fused_kernel(
    const float* __restrict__ q,        // [B,16]
    const float* __restrict__ frot,     // [16,3,3]
    const float* __restrict__ ftrans,   // [16,3]
    const float* __restrict__ axes,     // [16,3]
    const float* __restrict__ spheres,  // [16,8,4]
    float* __restrict__ out,            // [B,16]
    int B)
{
    __shared__ float4 sph[4 * 128];
    const int t    = threadIdx.x;
    const int w    = t >> 6;
    const int lane = t & 63;
    int b = blockIdx.x * 4 + w;
    const bool alive = (b < B);
    if (!alive) b = B - 1;              // clamp: do redundant work, guard stores

    const int l = lane & 15;            // link id this lane owns
    const int g = lane >> 4;            // sphere-group (which 2 of 8 spheres)

    // ---- local joint transform: R = F * J(axis,q) = F + s*(F K) + (1-c)*(F K K)
    const float qv = q[(size_t)b * 16 + l];
    const float s = sinf(qv), c = cosf(qv), oc = 1.0f - c;
    const float ax = axes[3*l+0], ay = axes[3*l+1], az = axes[3*l+2];

    const float F00=frot[9*l+0], F01=frot[9*l+1], F02=frot[9*l+2];
    const float F10=frot[9*l+3], F11=frot[9*l+4], F12=frot[9*l+5];
    const float F20=frot[9*l+6], F21=frot[9*l+7], F22=frot[9*l+8];

    float R00,R01,R02,R10,R11,R12,R20,R21,R22;
    {
        // row r of (F K) = cross(F_r, axis); row r of (F K K) = cross((F K)_r, axis)
        float u0 = fmaf(F01,az, -F02*ay);
        float u1 = fmaf(F02,ax, -F00*az);
        float u2 = fmaf(F00,ay, -F01*ax);
        float v0 = fmaf(u1,az, -u2*ay);
        float v1 = fmaf(u2,ax, -u0*az);
        float v2 = fmaf(u0,ay, -u1*ax);
        R00 = fmaf(oc,v0, fmaf(s,u0, F00));
        R01 = fmaf(oc,v1, fmaf(s,u1, F01));
        R02 = fmaf(oc,v2, fmaf(s,u2, F02));

        u0 = fmaf(F11,az, -F12*ay);
        u1 = fmaf(F12,ax, -F10*az);
        u2 = fmaf(F10,ay, -F11*ax);
        v0 = fmaf(u1,az, -u2*ay);
        v1 = fmaf(u2,ax, -u0*az);
        v2 = fmaf(u0,ay, -u1*ax);
        R10 = fmaf(oc,v0, fmaf(s,u0, F10));
        R11 = fmaf(oc,v1, fmaf(s,u1, F11));
        R12 = fmaf(oc,v2, fmaf(s,u2, F12));

        u0 = fmaf(F21,az, -F22*ay);
        u1 = fmaf(F22,ax, -F20*az);
        u2 = fmaf(F20,ay, -F21*ax);
        v0 = fmaf(u1,az, -u2*ay);
        v1 = fmaf(u2,ax, -u0*az);
        v2 = fmaf(u0,ay, -u1*ax);
        R20 = fmaf(oc,v0, fmaf(s,u0, F20));
        R21 = fmaf(oc,v1, fmaf(s,u1, F21));
        R22 = fmaf(oc,v2, fmaf(s,u2, F22));
    }
    float t0 = ftrans[3*l+0], t1 = ftrans[3*l+1], t2 = ftrans[3*l+2];

    // ---- inclusive prefix product over links (Kogge-Stone, width-16 segments)
    // lane l ends with T_l = M_0 * ... * M_l  (R, t)
    #pragma unroll
    for (int d = 1; d < 16; d <<= 1) {
        float P00 = __shfl_up(R00, d, 16), P01 = __shfl_up(R01, d, 16), P02 = __shfl_up(R02, d, 16);
        float P10 = __shfl_up(R10, d, 16), P11 = __shfl_up(R11, d, 16), P12 = __shfl_up(R12, d, 16);
        float P20 = __shfl_up(R20, d, 16), P21 = __shfl_up(R21, d, 16), P22 = __shfl_up(R22, d, 16);
        float pt0 = __shfl_up(t0,  d, 16), pt1 = __shfl_up(t1,  d, 16), pt2 = __shfl_up(t2,  d, 16);
        if (l >= d) {
            // new = P * cur   (rotation), new_t = P.R * cur_t + P.t
            float n00 = fmaf(P00,R00, fmaf(P01,R10, P02*R20));
            float n01 = fmaf(P00,R01, fmaf(P01,R11, P02*R21));
            float n02 = fmaf(P00,R02, fmaf(P01,R12, P02*R22));
            float n10 = fmaf(P10,R00, fmaf(P11,R10, P12*R20));
            float n11 = fmaf(P10,R01, fmaf(P11,R11, P12*R21));
            float n12 = fmaf(P10,R02, fmaf(P11,R12, P12*R22));
            float n20 = fmaf(P20,R00, fmaf(P21,R10, P22*R20));
            float n21 = fmaf(P20,R01, fmaf(P21,R11, P22*R21));
            float n22 = fmaf(P20,R02, fmaf(P21,R12, P22*R22));
            float nt0 = fmaf(P00,t0, fmaf(P01,t1, fmaf(P02,t2, pt0)));
            float nt1 = fmaf(P10,t0, fmaf(P11,t1, fmaf(P12,t2, pt1)));
            float nt2 = fmaf(P20,t0, fmaf(P21,t1, fmaf(P22,t2, pt2)));
            R00=n00; R01=n01; R02=n02;
            R10=n10; R11=n11; R12=n12;
            R20=n20; R21=n21; R22=n22;
            t0=nt0; t1=nt1; t2=nt2;
        }
    }

    // ---- transform this lane's 2 spheres of link l into LDS
    #pragma unroll
    for (int k = 0; k < 2; ++k) {
        const int sp = g * 2 + k;
        float4 cs = reinterpret_cast<const float4*>(spheres)[l*8 + sp];
        float wx = fmaf(R00,cs.x, fmaf(R01,cs.y, fmaf(R02,cs.z, t0)));
        float wy = fmaf(R10,cs.x, fmaf(R11,cs.y, fmaf(R12,cs.z, t1)));
        float wz = fmaf(R20,cs.x, fmaf(R21,cs.y, fmaf(R22,cs.z, t2)));
        sph[w*128 + l*8 + sp] = make_float4(wx, wy, wz, cs.w);
    }
    __syncthreads();

    // ---- pairwise penetration, per-link max
    const float4* S = &sph[w * 128];
    const int sr = lane >> 3;
    const int sc = lane & 7;

    float4 cs[16];
    #pragma unroll
    for (int j = 0; j < 16; ++j) cs[j] = S[j*8 + sc];

    float m[16];
    #pragma unroll
    for (int k = 0; k < 16; ++k) m[k] = -100.0f;

    #pragma unroll
    for (int i = 0; i < 14; ++i) {
        float4 rs = S[i*8 + sr];
        #pragma unroll
        for (int j = i + 2; j < 16; ++j) {
            float dx = rs.x - cs[j].x;
            float dy = rs.y - cs[j].y;
            float dz = rs.z - cs[j].z;
            float d2 = fmaf(dx,dx, fmaf(dy,dy, dz*dz));
            d2 = fmaxf(d2, 1e-12f);
            float pen = rs.w + cs[j].w - __builtin_amdgcn_sqrtf(d2);
            m[i] = fmaxf(m[i], pen);
            m[j] = fmaxf(m[j], pen);
        }
    }

    // wave-wide max per link (butterfly leaves result in all lanes)
    #pragma unroll
    for (int k = 0; k < 16; ++k) {
        float v = m[k];
        #pragma unroll
        for (int off = 32; off > 0; off >>= 1)
            v = fmaxf(v, __shfl_xor(v, off, 64));
        m[k] = v;
    }

    // vectorized store: lanes 0..3 write one float4 each
    if (alive && lane < 4) {
        float4 o = make_float4(m[lane*4+0], m[lane*4+1], m[lane*4+2], m[lane*4+3]);
        reinterpret_cast<float4*>(out)[(size_t)b*4 + lane] = o;
    }
}

// ---------------------------------------------------------------------------
extern "C" void kernel_launch(void* const* d_in, const int* in_sizes, int n_in,
                              void* d_out, int out_size, void* d_ws, size_t ws_size,
                              hipStream_t stream) {
    const float* q      = (const float*)d_in[0];
    const float* frot   = (const float*)d_in[1];
    const float* ftrans = (const float*)d_in[2];
    const float* axes   = (const float*)d_in[3];
    const float* sphere = (const float*)d_in[4];
    // d_in[5] (collision_mask) is deterministically |i-j|>1 -> computed inline.
    float* out = (float*)d_out;

    const int B = in_sizes[0] / 16;
    const int blocks = (B + 3) / 4;     // 1 wave per batch, 4 waves per block
    fused_kernel<<<dim3(blocks), dim3(256), 0, stream>>>(
        q, frot, ftrans, axes, sphere, out, B);
}

// Round 3
// 27.179 us; speedup vs baseline: 2.0739x; 1.2409x over previous
//
#include <hip/hip_runtime.h>

// ---------------------------------------------------------------------------
// Fully fused, one wave per batch element (4 waves / 256-thread block).
//  - FK via 4-step Kogge-Stone prefix product over 16 joints (width-16 shfl).
//  - Spheres transformed into padded LDS (stride 9 float4 -> no bank conflict).
//  - Pair loop split into two register-tiled passes so the 7-entry cs cache
//    stays in VGPRs (no LDS reloads).
//  - Per-link wave max via log-fold: 17 shuffles instead of 96.
// ---------------------------------------------------------------------------
__global__ __launch_bounds__(256) void fused_kernel(
    const float* __restrict__ q,        // [B,16]
    const float* __restrict__ frot,     // [16,3,3]
    const float* __restrict__ ftrans,   // [16,3]
    const float* __restrict__ axes,     // [16,3]
    const float* __restrict__ spheres,  // [16,8,4]
    float* __restrict__ out,            // [B,16]
    int B)
{
    __shared__ float4 sph[4][16 * 9];   // 9 float4 per link: +1 pad row
    const int t    = threadIdx.x;
    const int w    = t >> 6;
    const int lane = t & 63;
    int b = blockIdx.x * 4 + w;
    const bool alive = (b < B);
    if (!alive) b = B - 1;

    const int l = lane & 15;            // link this lane owns in FK phase
    const int g = lane >> 4;            // sphere-group (2 spheres each)

    // ---- local joint transform: R = F * J(axis,q)
    const float qv = q[(size_t)b * 16 + l];
    const float s = __sinf(qv), c = __cosf(qv), oc = 1.0f - c;
    const float ax = axes[3*l+0], ay = axes[3*l+1], az = axes[3*l+2];

    const float F00=frot[9*l+0], F01=frot[9*l+1], F02=frot[9*l+2];
    const float F10=frot[9*l+3], F11=frot[9*l+4], F12=frot[9*l+5];
    const float F20=frot[9*l+6], F21=frot[9*l+7], F22=frot[9*l+8];

    float R00,R01,R02,R10,R11,R12,R20,R21,R22;
    {
        float u0 = fmaf(F01,az, -F02*ay);
        float u1 = fmaf(F02,ax, -F00*az);
        float u2 = fmaf(F00,ay, -F01*ax);
        float v0 = fmaf(u1,az, -u2*ay);
        float v1 = fmaf(u2,ax, -u0*az);
        float v2 = fmaf(u0,ay, -u1*ax);
        R00 = fmaf(oc,v0, fmaf(s,u0, F00));
        R01 = fmaf(oc,v1, fmaf(s,u1, F01));
        R02 = fmaf(oc,v2, fmaf(s,u2, F02));

        u0 = fmaf(F11,az, -F12*ay);
        u1 = fmaf(F12,ax, -F10*az);
        u2 = fmaf(F10,ay, -F11*ax);
        v0 = fmaf(u1,az, -u2*ay);
        v1 = fmaf(u2,ax, -u0*az);
        v2 = fmaf(u0,ay, -u1*ax);
        R10 = fmaf(oc,v0, fmaf(s,u0, F10));
        R11 = fmaf(oc,v1, fmaf(s,u1, F11));
        R12 = fmaf(oc,v2, fmaf(s,u2, F12));

        u0 = fmaf(F21,az, -F22*ay);
        u1 = fmaf(F22,ax, -F20*az);
        u2 = fmaf(F20,ay, -F21*ax);
        v0 = fmaf(u1,az, -u2*ay);
        v1 = fmaf(u2,ax, -u0*az);
        v2 = fmaf(u0,ay, -u1*ax);
        R20 = fmaf(oc,v0, fmaf(s,u0, F20));
        R21 = fmaf(oc,v1, fmaf(s,u1, F21));
        R22 = fmaf(oc,v2, fmaf(s,u2, F22));
    }
    float t0 = ftrans[3*l+0], t1 = ftrans[3*l+1], t2 = ftrans[3*l+2];

    // ---- Kogge-Stone inclusive prefix product (width-16 segments)
    #pragma unroll
    for (int d = 1; d < 16; d <<= 1) {
        float P00 = __shfl_up(R00, d, 16), P01 = __shfl_up(R01, d, 16), P02 = __shfl_up(R02, d, 16);
        float P10 = __shfl_up(R10, d, 16), P11 = __shfl_up(R11, d, 16), P12 = __shfl_up(R12, d, 16);
        float P20 = __shfl_up(R20, d, 16), P21 = __shfl_up(R21, d, 16), P22 = __shfl_up(R22, d, 16);
        float pt0 = __shfl_up(t0,  d, 16), pt1 = __shfl_up(t1,  d, 16), pt2 = __shfl_up(t2,  d, 16);
        if (l >= d) {
            float n00 = fmaf(P00,R00, fmaf(P01,R10, P02*R20));
            float n01 = fmaf(P00,R01, fmaf(P01,R11, P02*R21));
            float n02 = fmaf(P00,R02, fmaf(P01,R12, P02*R22));
            float n10 = fmaf(P10,R00, fmaf(P11,R10, P12*R20));
            float n11 = fmaf(P10,R01, fmaf(P11,R11, P12*R21));
            float n12 = fmaf(P10,R02, fmaf(P11,R12, P12*R22));
            float n20 = fmaf(P20,R00, fmaf(P21,R10, P22*R20));
            float n21 = fmaf(P20,R01, fmaf(P21,R11, P22*R21));
            float n22 = fmaf(P20,R02, fmaf(P21,R12, P22*R22));
            float nt0 = fmaf(P00,t0, fmaf(P01,t1, fmaf(P02,t2, pt0)));
            float nt1 = fmaf(P10,t0, fmaf(P11,t1, fmaf(P12,t2, pt1)));
            float nt2 = fmaf(P20,t0, fmaf(P21,t1, fmaf(P22,t2, pt2)));
            R00=n00; R01=n01; R02=n02;
            R10=n10; R11=n11; R12=n12;
            R20=n20; R21=n21; R22=n22;
            t0=nt0; t1=nt1; t2=nt2;
        }
    }

    // ---- transform this lane's 2 spheres of link l into padded LDS
    #pragma unroll
    for (int k = 0; k < 2; ++k) {
        const int sp = g * 2 + k;
        float4 cs = reinterpret_cast<const float4*>(spheres)[l*8 + sp];
        float wx = fmaf(R00,cs.x, fmaf(R01,cs.y, fmaf(R02,cs.z, t0)));
        float wy = fmaf(R10,cs.x, fmaf(R11,cs.y, fmaf(R12,cs.z, t1)));
        float wz = fmaf(R20,cs.x, fmaf(R21,cs.y, fmaf(R22,cs.z, t2)));
        sph[w][l*9 + sp] = make_float4(wx, wy, wz, cs.w);
    }
    // Each wave reads only its own slice -> no block barrier needed, just
    // drain this wave's LDS writes before the reads below.
    asm volatile("s_waitcnt lgkmcnt(0)" ::: "memory");

    // ---- pairwise penetration, per-link max (two register-tiled passes)
    const float4* S = sph[w];
    const int sr = lane >> 3;
    const int sc = lane & 7;

    float m[16];
    #pragma unroll
    for (int k = 0; k < 16; ++k) m[k] = -100.0f;

    // Pass A: columns j in [2,8], rows i in [0,6] (j >= i+2)
    {
        float4 cs[7];
        #pragma unroll
        for (int j = 2; j <= 8; ++j) cs[j-2] = S[j*9 + sc];
        #pragma unroll
        for (int i = 0; i <= 6; ++i) {
            float4 rs = S[i*9 + sr];
            #pragma unroll
            for (int j = i + 2; j <= 8; ++j) {
                float dx = rs.x - cs[j-2].x;
                float dy = rs.y - cs[j-2].y;
                float dz = rs.z - cs[j-2].z;
                float d2 = fmaf(dx,dx, fmaf(dy,dy, dz*dz));
                float pen = rs.w + cs[j-2].w - __builtin_amdgcn_sqrtf(d2);
                m[i] = fmaxf(m[i], pen);
                m[j] = fmaxf(m[j], pen);
            }
        }
    }
    // Pass B: columns j in [9,15], rows i in [0,13] (j >= i+2)
    {
        float4 cs[7];
        #pragma unroll
        for (int j = 9; j <= 15; ++j) cs[j-9] = S[j*9 + sc];
        #pragma unroll
        for (int i = 0; i <= 13; ++i) {
            float4 rs = S[i*9 + sr];
            const int j0 = (i + 2 > 9) ? (i + 2) : 9;
            #pragma unroll
            for (int j = 9; j <= 15; ++j) {
                if (j < j0) continue;
                float dx = rs.x - cs[j-9].x;
                float dy = rs.y - cs[j-9].y;
                float dz = rs.z - cs[j-9].z;
                float d2 = fmaf(dx,dx, fmaf(dy,dy, dz*dz));
                float pen = rs.w + cs[j-9].w - __builtin_amdgcn_sqrtf(d2);
                m[i] = fmaxf(m[i], pen);
                m[j] = fmaxf(m[j], pen);
            }
        }
    }

    // ---- log-fold wave reduction: 16 values over 64 lanes in 17 shuffles.
    // After fold k with xor (1<<k), lane keeps half selected by its bit k;
    // final link index = bit-reverse of (lane & 15).
    {
        int bit0 = lane & 1;
        #pragma unroll
        for (int k = 0; k < 8; ++k) {
            float send = bit0 ? m[k] : m[k+8];
            float recv = __shfl_xor(send, 1, 64);
            m[k] = fmaxf(bit0 ? m[k+8] : m[k], recv);
        }
        int bit1 = (lane >> 1) & 1;
        #pragma unroll
        for (int k = 0; k < 4; ++k) {
            float send = bit1 ? m[k] : m[k+4];
            float recv = __shfl_xor(send, 2, 64);
            m[k] = fmaxf(bit1 ? m[k+4] : m[k], recv);
        }
        int bit2 = (lane >> 2) & 1;
        #pragma unroll
        for (int k = 0; k < 2; ++k) {
            float send = bit2 ? m[k] : m[k+2];
            float recv = __shfl_xor(send, 4, 64);
            m[k] = fmaxf(bit2 ? m[k+2] : m[k], recv);
        }
        int bit3 = (lane >> 3) & 1;
        {
            float send = bit3 ? m[0] : m[1];
            float recv = __shfl_xor(send, 8, 64);
            m[0] = fmaxf(bit3 ? m[1] : m[0], recv);
        }
        float v = m[0];
        v = fmaxf(v, __shfl_xor(v, 16, 64));
        v = fmaxf(v, __shfl_xor(v, 32, 64));
        m[0] = v;
    }

    if (alive && lane < 16) {
        // link index = bit-reversal of lane's low 4 bits
        int k = ((lane & 1) << 3) | ((lane & 2) << 1) | ((lane & 4) >> 1) | ((lane & 8) >> 3);
        out[(size_t)b * 16 + k] = m[0];
    }
}

// ---------------------------------------------------------------------------
extern "C" void kernel_launch(void* const* d_in, const int* in_sizes, int n_in,
                              void* d_out, int out_size, void* d_ws, size_t ws_size,
                              hipStream_t stream) {
    const float* q      = (const float*)d_in[0];
    const float* frot   = (const float*)d_in[1];
    const float* ftrans = (const float*)d_in[2];
    const float* axes   = (const float*)d_in[3];
    const float* sphere = (const float*)d_in[4];
    // d_in[5] (collision_mask) is deterministically |i-j|>1 -> computed inline.
    float* out = (float*)d_out;

    const int B = in_sizes[0] / 16;
    const int blocks = (B + 3) / 4;
    fused_kernel<<<dim3(blocks), dim3(256), 0, stream>>>(
        q, frot, ftrans, axes, sphere, out, B);
}

// Round 4
// 23.317 us; speedup vs baseline: 2.4173x; 1.1656x over previous
//
#include <hip/hip_runtime.h>

typedef float v2f __attribute__((ext_vector_type(2)));

// compile-time DPP move: dest lane gets src lane per CTRL pattern
template<int CTRL>
__device__ __forceinline__ float dppmov(float x) {
    return __builtin_bit_cast(float,
        __builtin_amdgcn_update_dpp(0, __builtin_bit_cast(int, x),
                                    CTRL, 0xf, 0xf, true));
}
// DPP ctrl encodings: quad_perm 0x00-0xFF; row_shr:N = 0x110|N; row_ror:N = 0x120|N
#define DPP_XOR1  0xB1   // quad_perm [1,0,3,2]
#define DPP_XOR2  0x4E   // quad_perm [2,3,0,1]
#define DPP_XOR8  0x128  // row_ror:8 == lane^8 within 16
#define DPP_SHR(d) (0x110 | (d))

// packed penetration: rows r0,r1 vs column sphere c; updates m[i0],m[i1],m[j]
__device__ __forceinline__ void pen2(const float4& r0, const float4& r1,
                                     const float4& c,
                                     float& m0, float& m1, float& mj)
{
    v2f dx = (v2f){r0.x, r1.x} - c.x;
    v2f dy = (v2f){r0.y, r1.y} - c.y;
    v2f dz = (v2f){r0.z, r1.z} - c.z;
    v2f d2 = dx * dx;
    d2 = __builtin_elementwise_fma(dy, dy, d2);
    d2 = __builtin_elementwise_fma(dz, dz, d2);
    float s0 = __builtin_amdgcn_sqrtf(d2.x);
    float s1 = __builtin_amdgcn_sqrtf(d2.y);
    v2f pen = ((v2f){r0.w, r1.w} + c.w) - (v2f){s0, s1};
    m0 = fmaxf(m0, pen.x);
    m1 = fmaxf(m1, pen.y);
    mj = fmaxf(fmaxf(mj, pen.x), pen.y);   // v_max3_f32 candidate
}

__device__ __forceinline__ void pen1(const float4& r, const float4& c,
                                     float& mi, float& mj)
{
    float dx = r.x - c.x, dy = r.y - c.y, dz = r.z - c.z;
    float d2 = fmaf(dx, dx, fmaf(dy, dy, dz * dz));
    float p  = r.w + c.w - __builtin_amdgcn_sqrtf(d2);
    mi = fmaxf(mi, p);
    mj = fmaxf(mj, p);
}

// ---------------------------------------------------------------------------
// Fully fused, one wave per batch element (4 waves / 256-thread block).
//  - FK prefix product via DPP row_shr (VALU pipe, no DS traffic).
//  - Spheres in padded LDS (stride 9 float4) -> conflict-free ds_read_b128.
//  - Pair loop: v_pk_f32-packed over row-pairs, cs column cache reg-tiled
//    in two passes; m[j] via max3.
//  - Per-link wave max: log-fold, DPP for xor1/2/8, shfl for xor4/16/32.
// ---------------------------------------------------------------------------
__global__ __launch_bounds__(256) void fused_kernel(
    const float* __restrict__ q,        // [B,16]
    const float* __restrict__ frot,     // [16,3,3]
    const float* __restrict__ ftrans,   // [16,3]
    const float* __restrict__ axes,     // [16,3]
    const float* __restrict__ spheres,  // [16,8,4]
    float* __restrict__ out,            // [B,16]
    int B)
{
    __shared__ float4 sph[4][16 * 9];
    const int t    = threadIdx.x;
    const int w    = t >> 6;
    const int lane = t & 63;
    int b = blockIdx.x * 4 + w;
    const bool alive = (b < B);
    if (!alive) b = B - 1;

    const int l = lane & 15;
    const int g = lane >> 4;

    // ---- local joint transform: R = F * J(axis,q)
    const float qv = q[(size_t)b * 16 + l];
    const float s = __sinf(qv), c = __cosf(qv), oc = 1.0f - c;
    const float ax = axes[3*l+0], ay = axes[3*l+1], az = axes[3*l+2];

    const float F00=frot[9*l+0], F01=frot[9*l+1], F02=frot[9*l+2];
    const float F10=frot[9*l+3], F11=frot[9*l+4], F12=frot[9*l+5];
    const float F20=frot[9*l+6], F21=frot[9*l+7], F22=frot[9*l+8];

    float R00,R01,R02,R10,R11,R12,R20,R21,R22;
    {
        float u0 = fmaf(F01,az, -F02*ay);
        float u1 = fmaf(F02,ax, -F00*az);
        float u2 = fmaf(F00,ay, -F01*ax);
        float v0 = fmaf(u1,az, -u2*ay);
        float v1 = fmaf(u2,ax, -u0*az);
        float v2 = fmaf(u0,ay, -u1*ax);
        R00 = fmaf(oc,v0, fmaf(s,u0, F00));
        R01 = fmaf(oc,v1, fmaf(s,u1, F01));
        R02 = fmaf(oc,v2, fmaf(s,u2, F02));

        u0 = fmaf(F11,az, -F12*ay);
        u1 = fmaf(F12,ax, -F10*az);
        u2 = fmaf(F10,ay, -F11*ax);
        v0 = fmaf(u1,az, -u2*ay);
        v1 = fmaf(u2,ax, -u0*az);
        v2 = fmaf(u0,ay, -u1*ax);
        R10 = fmaf(oc,v0, fmaf(s,u0, F10));
        R11 = fmaf(oc,v1, fmaf(s,u1, F11));
        R12 = fmaf(oc,v2, fmaf(s,u2, F12));

        u0 = fmaf(F21,az, -F22*ay);
        u1 = fmaf(F22,ax, -F20*az);
        u2 = fmaf(F20,ay, -F21*ax);
        v0 = fmaf(u1,az, -u2*ay);
        v1 = fmaf(u2,ax, -u0*az);
        v2 = fmaf(u0,ay, -u1*ax);
        R20 = fmaf(oc,v0, fmaf(s,u0, F20));
        R21 = fmaf(oc,v1, fmaf(s,u1, F21));
        R22 = fmaf(oc,v2, fmaf(s,u2, F22));
    }
    float t0 = ftrans[3*l+0], t1 = ftrans[3*l+1], t2 = ftrans[3*l+2];

    // ---- Kogge-Stone prefix product, shuffles done on the VALU pipe via DPP
    #define SCAN_STEP(D, CTRL)                                                  \
    {                                                                           \
        float P00 = dppmov<CTRL>(R00), P01 = dppmov<CTRL>(R01), P02 = dppmov<CTRL>(R02); \
        float P10 = dppmov<CTRL>(R10), P11 = dppmov<CTRL>(R11), P12 = dppmov<CTRL>(R12); \
        float P20 = dppmov<CTRL>(R20), P21 = dppmov<CTRL>(R21), P22 = dppmov<CTRL>(R22); \
        float pt0 = dppmov<CTRL>(t0),  pt1 = dppmov<CTRL>(t1),  pt2 = dppmov<CTRL>(t2);  \
        if (l >= (D)) {                                                         \
            float n00 = fmaf(P00,R00, fmaf(P01,R10, P02*R20));                  \
            float n01 = fmaf(P00,R01, fmaf(P01,R11, P02*R21));                  \
            float n02 = fmaf(P00,R02, fmaf(P01,R12, P02*R22));                  \
            float n10 = fmaf(P10,R00, fmaf(P11,R10, P12*R20));                  \
            float n11 = fmaf(P10,R01, fmaf(P11,R11, P12*R21));                  \
            float n12 = fmaf(P10,R02, fmaf(P11,R12, P12*R22));                  \
            float n20 = fmaf(P20,R00, fmaf(P21,R10, P22*R20));                  \
            float n21 = fmaf(P20,R01, fmaf(P21,R11, P22*R21));                  \
            float n22 = fmaf(P20,R02, fmaf(P21,R12, P22*R22));                  \
            float nt0 = fmaf(P00,t0, fmaf(P01,t1, fmaf(P02,t2, pt0)));          \
            float nt1 = fmaf(P10,t0, fmaf(P11,t1, fmaf(P12,t2, pt1)));          \
            float nt2 = fmaf(P20,t0, fmaf(P21,t1, fmaf(P22,t2, pt2)));          \
            R00=n00; R01=n01; R02=n02;                                          \
            R10=n10; R11=n11; R12=n12;                                          \
            R20=n20; R21=n21; R22=n22;                                          \
            t0=nt0; t1=nt1; t2=nt2;                                             \
        }                                                                       \
    }
    SCAN_STEP(1, DPP_SHR(1))
    SCAN_STEP(2, DPP_SHR(2))
    SCAN_STEP(4, DPP_SHR(4))
    SCAN_STEP(8, DPP_SHR(8))
    #undef SCAN_STEP

    // ---- transform this lane's 2 spheres of link l into padded LDS
    #pragma unroll
    for (int k = 0; k < 2; ++k) {
        const int sp = g * 2 + k;
        float4 cs = reinterpret_cast<const float4*>(spheres)[l*8 + sp];
        float wx = fmaf(R00,cs.x, fmaf(R01,cs.y, fmaf(R02,cs.z, t0)));
        float wy = fmaf(R10,cs.x, fmaf(R11,cs.y, fmaf(R12,cs.z, t1)));
        float wz = fmaf(R20,cs.x, fmaf(R21,cs.y, fmaf(R22,cs.z, t2)));
        sph[w][l*9 + sp] = make_float4(wx, wy, wz, cs.w);
    }
    asm volatile("s_waitcnt lgkmcnt(0)" ::: "memory");

    const float4* S = sph[w];
    const int sr = lane >> 3;
    const int sc = lane & 7;

    float m[16];
    #pragma unroll
    for (int k = 0; k < 16; ++k) m[k] = -100.0f;

    // ---- Pass A: columns j in [2,8]
    {
        float4 cs[7];
        #pragma unroll
        for (int j = 2; j <= 8; ++j) cs[j-2] = S[j*9 + sc];

        float4 r0 = S[0*9 + sr], r1 = S[1*9 + sr];
        pen1(r0, cs[0], m[0], m[2]);                       // (0,2)
        #pragma unroll
        for (int j = 3; j <= 8; ++j) pen2(r0, r1, cs[j-2], m[0], m[1], m[j]);

        r0 = S[2*9 + sr]; r1 = S[3*9 + sr];
        pen1(r0, cs[2], m[2], m[4]);                       // (2,4)
        #pragma unroll
        for (int j = 5; j <= 8; ++j) pen2(r0, r1, cs[j-2], m[2], m[3], m[j]);

        r0 = S[4*9 + sr]; r1 = S[5*9 + sr];
        pen1(r0, cs[4], m[4], m[6]);                       // (4,6)
        #pragma unroll
        for (int j = 7; j <= 8; ++j) pen2(r0, r1, cs[j-2], m[4], m[5], m[j]);

        r0 = S[6*9 + sr];
        pen1(r0, cs[6], m[6], m[8]);                       // (6,8)
    }

    // ---- Pass B: columns j in [9,15]
    {
        float4 cs[7];
        #pragma unroll
        for (int j = 9; j <= 15; ++j) cs[j-9] = S[j*9 + sc];

        #pragma unroll
        for (int k = 0; k < 4; ++k) {                      // row-pairs (0,1)..(6,7)
            float4 r0 = S[(2*k)*9 + sr], r1 = S[(2*k+1)*9 + sr];
            #pragma unroll
            for (int j = 9; j <= 15; ++j) pen2(r0, r1, cs[j-9], m[2*k], m[2*k+1], m[j]);
        }

        float4 r0 = S[8*9 + sr], r1 = S[9*9 + sr];
        pen1(r0, cs[1], m[8], m[10]);                      // (8,10)
        #pragma unroll
        for (int j = 11; j <= 15; ++j) pen2(r0, r1, cs[j-9], m[8], m[9], m[j]);

        r0 = S[10*9 + sr]; r1 = S[11*9 + sr];
        pen1(r0, cs[3], m[10], m[12]);                     // (10,12)
        #pragma unroll
        for (int j = 13; j <= 15; ++j) pen2(r0, r1, cs[j-9], m[10], m[11], m[j]);

        r0 = S[12*9 + sr]; r1 = S[13*9 + sr];
        pen1(r0, cs[5], m[12], m[14]);                     // (12,14)
        pen2(r0, r1, cs[6], m[12], m[13], m[15]);          // (12,15),(13,15)
    }

    // ---- log-fold wave reduction (17 exchanges: 13 DPP + 4 DS)
    {
        int bit0 = lane & 1;
        #pragma unroll
        for (int k = 0; k < 8; ++k) {
            float send = bit0 ? m[k] : m[k+8];
            float recv = dppmov<DPP_XOR1>(send);
            m[k] = fmaxf(bit0 ? m[k+8] : m[k], recv);
        }
        int bit1 = (lane >> 1) & 1;
        #pragma unroll
        for (int k = 0; k < 4; ++k) {
            float send = bit1 ? m[k] : m[k+4];
            float recv = dppmov<DPP_XOR2>(send);
            m[k] = fmaxf(bit1 ? m[k+4] : m[k], recv);
        }
        int bit2 = (lane >> 2) & 1;
        #pragma unroll
        for (int k = 0; k < 2; ++k) {
            float send = bit2 ? m[k] : m[k+2];
            float recv = __shfl_xor(send, 4, 64);
            m[k] = fmaxf(bit2 ? m[k+2] : m[k], recv);
        }
        int bit3 = (lane >> 3) & 1;
        {
            float send = bit3 ? m[0] : m[1];
            float recv = dppmov<DPP_XOR8>(send);
            m[0] = fmaxf(bit3 ? m[1] : m[0], recv);
        }
        float v = m[0];
        v = fmaxf(v, __shfl_xor(v, 16, 64));
        v = fmaxf(v, __shfl_xor(v, 32, 64));
        m[0] = v;
    }

    if (alive && lane < 16) {
        int k = ((lane & 1) << 3) | ((lane & 2) << 1) | ((lane & 4) >> 1) | ((lane & 8) >> 3);
        out[(size_t)b * 16 + k] = m[0];
    }
}

// ---------------------------------------------------------------------------
extern "C" void kernel_launch(void* const* d_in, const int* in_sizes, int n_in,
                              void* d_out, int out_size, void* d_ws, size_t ws_size,
                              hipStream_t stream) {
    const float* q      = (const float*)d_in[0];
    const float* frot   = (const float*)d_in[1];
    const float* ftrans = (const float*)d_in[2];
    const float* axes   = (const float*)d_in[3];
    const float* sphere = (const float*)d_in[4];
    float* out = (float*)d_out;

    const int B = in_sizes[0] / 16;
    const int blocks = (B + 3) / 4;
    fused_kernel<<<dim3(blocks), dim3(256), 0, stream>>>(
        q, frot, ftrans, axes, sphere, out, B);
}

// Round 5
// 20.556 us; speedup vs baseline: 2.7420x; 1.1343x over previous
//
#include <hip/hip_runtime.h>

typedef float v2f __attribute__((ext_vector_type(2)));

// compile-time DPP move: dest lane gets src lane per CTRL pattern
template<int CTRL>
__device__ __forceinline__ float dppmov(float x) {
    return __builtin_bit_cast(float,
        __builtin_amdgcn_update_dpp(0, __builtin_bit_cast(int, x),
                                    CTRL, 0xf, 0xf, true));
}
#define DPP_XOR1  0xB1   // quad_perm [1,0,3,2]
#define DPP_XOR2  0x4E   // quad_perm [2,3,0,1]
#define DPP_XOR8  0x128  // row_ror:8 == lane^8 within 16-lane rows
#define DPP_SHR(d) (0x110 | (d))

// packed penetration: one row sphere vs packed column spheres {sc2, sc2+4}
// of the SAME link j -> both lanes' maxes fold with v_max3.
__device__ __forceinline__ void pen2p(const float4& rs,
                                      v2f cx, v2f cy, v2f cz, v2f cw,
                                      float& mi, float& mj)
{
    v2f dx = cx - rs.x;
    v2f dy = cy - rs.y;
    v2f dz = cz - rs.z;
    v2f d2 = dx * dx;
    d2 = __builtin_elementwise_fma(dy, dy, d2);
    d2 = __builtin_elementwise_fma(dz, dz, d2);
    v2f pen = (cw + rs.w) - (v2f){__builtin_amdgcn_sqrtf(d2.x),
                                  __builtin_amdgcn_sqrtf(d2.y)};
    mi = fmaxf(fmaxf(mi, pen.x), pen.y);   // v_max3_f32
    mj = fmaxf(fmaxf(mj, pen.x), pen.y);   // v_max3_f32
}

// ---------------------------------------------------------------------------
// Fully fused, TWO batches per wave (lanes 0-31 batch A, 32-63 batch B).
//  - FK prefix product via DPP row_shr; 16-lane groups (0,1)->A, (2,3)->B
//    (scan redundancy 2x instead of 4x).
//  - Each lane transforms 4 spheres of its link into padded LDS.
//  - Pair phase: 32 lanes per batch; lane owns (row sr = L>>2, cols {sc2,sc2+4});
//    column cache register-tiled in two passes as born-packed v2f via paired
//    LDS scalar loads (ds_read2_b32).
//  - Per-link max: log-fold over 32 lanes (13 DPP + 2 DS exchanges).
// ---------------------------------------------------------------------------
__global__ __launch_bounds__(256, 4) void fused_kernel(
    const float* __restrict__ q,        // [B,16]
    const float* __restrict__ frot,     // [16,3,3]
    const float* __restrict__ ftrans,   // [16,3]
    const float* __restrict__ axes,     // [16,3]
    const float* __restrict__ spheres,  // [16,8,4]
    float* __restrict__ out,            // [B,16]
    int B)
{
    __shared__ float4 sph[4][2][16 * 9];   // [wave][batch-half][link*9 + sphere]
    const int t    = threadIdx.x;
    const int w    = t >> 6;
    const int lane = t & 63;
    const int h    = lane >> 5;            // batch half within wave
    int b = blockIdx.x * 8 + w * 2 + h;
    const bool alive = (b < B);
    if (!alive) b = B - 1;

    const int l = lane & 15;               // link this lane owns in FK phase
    const int g = (lane >> 4) & 1;         // sphere-group (4 spheres each)

    // ---- local joint transform: R = F * J(axis,q)
    const float qv = q[(size_t)b * 16 + l];
    const float s = __sinf(qv), c = __cosf(qv), oc = 1.0f - c;
    const float ax = axes[3*l+0], ay = axes[3*l+1], az = axes[3*l+2];

    const float F00=frot[9*l+0], F01=frot[9*l+1], F02=frot[9*l+2];
    const float F10=frot[9*l+3], F11=frot[9*l+4], F12=frot[9*l+5];
    const float F20=frot[9*l+6], F21=frot[9*l+7], F22=frot[9*l+8];

    float R00,R01,R02,R10,R11,R12,R20,R21,R22;
    {
        float u0 = fmaf(F01,az, -F02*ay);
        float u1 = fmaf(F02,ax, -F00*az);
        float u2 = fmaf(F00,ay, -F01*ax);
        float v0 = fmaf(u1,az, -u2*ay);
        float v1 = fmaf(u2,ax, -u0*az);
        float v2 = fmaf(u0,ay, -u1*ax);
        R00 = fmaf(oc,v0, fmaf(s,u0, F00));
        R01 = fmaf(oc,v1, fmaf(s,u1, F01));
        R02 = fmaf(oc,v2, fmaf(s,u2, F02));

        u0 = fmaf(F11,az, -F12*ay);
        u1 = fmaf(F12,ax, -F10*az);
        u2 = fmaf(F10,ay, -F11*ax);
        v0 = fmaf(u1,az, -u2*ay);
        v1 = fmaf(u2,ax, -u0*az);
        v2 = fmaf(u0,ay, -u1*ax);
        R10 = fmaf(oc,v0, fmaf(s,u0, F10));
        R11 = fmaf(oc,v1, fmaf(s,u1, F11));
        R12 = fmaf(oc,v2, fmaf(s,u2, F12));

        u0 = fmaf(F21,az, -F22*ay);
        u1 = fmaf(F22,ax, -F20*az);
        u2 = fmaf(F20,ay, -F21*ax);
        v0 = fmaf(u1,az, -u2*ay);
        v1 = fmaf(u2,ax, -u0*az);
        v2 = fmaf(u0,ay, -u1*ax);
        R20 = fmaf(oc,v0, fmaf(s,u0, F20));
        R21 = fmaf(oc,v1, fmaf(s,u1, F21));
        R22 = fmaf(oc,v2, fmaf(s,u2, F22));
    }
    float t0 = ftrans[3*l+0], t1 = ftrans[3*l+1], t2 = ftrans[3*l+2];

    // ---- Kogge-Stone prefix product over width-16 segments (DPP row_shr)
    #define SCAN_STEP(D, CTRL)                                                  \
    {                                                                           \
        float P00 = dppmov<CTRL>(R00), P01 = dppmov<CTRL>(R01), P02 = dppmov<CTRL>(R02); \
        float P10 = dppmov<CTRL>(R10), P11 = dppmov<CTRL>(R11), P12 = dppmov<CTRL>(R12); \
        float P20 = dppmov<CTRL>(R20), P21 = dppmov<CTRL>(R21), P22 = dppmov<CTRL>(R22); \
        float pt0 = dppmov<CTRL>(t0),  pt1 = dppmov<CTRL>(t1),  pt2 = dppmov<CTRL>(t2);  \
        if (l >= (D)) {                                                         \
            float n00 = fmaf(P00,R00, fmaf(P01,R10, P02*R20));                  \
            float n01 = fmaf(P00,R01, fmaf(P01,R11, P02*R21));                  \
            float n02 = fmaf(P00,R02, fmaf(P01,R12, P02*R22));                  \
            float n10 = fmaf(P10,R00, fmaf(P11,R10, P12*R20));                  \
            float n11 = fmaf(P10,R01, fmaf(P11,R11, P12*R21));                  \
            float n12 = fmaf(P10,R02, fmaf(P11,R12, P12*R22));                  \
            float n20 = fmaf(P20,R00, fmaf(P21,R10, P22*R20));                  \
            float n21 = fmaf(P20,R01, fmaf(P21,R11, P22*R21));                  \
            float n22 = fmaf(P20,R02, fmaf(P21,R12, P22*R22));                  \
            float nt0 = fmaf(P00,t0, fmaf(P01,t1, fmaf(P02,t2, pt0)));          \
            float nt1 = fmaf(P10,t0, fmaf(P11,t1, fmaf(P12,t2, pt1)));          \
            float nt2 = fmaf(P20,t0, fmaf(P21,t1, fmaf(P22,t2, pt2)));          \
            R00=n00; R01=n01; R02=n02;                                          \
            R10=n10; R11=n11; R12=n12;                                          \
            R20=n20; R21=n21; R22=n22;                                          \
            t0=nt0; t1=nt1; t2=nt2;                                             \
        }                                                                       \
    }
    SCAN_STEP(1, DPP_SHR(1))
    SCAN_STEP(2, DPP_SHR(2))
    SCAN_STEP(4, DPP_SHR(4))
    SCAN_STEP(8, DPP_SHR(8))
    #undef SCAN_STEP

    // ---- transform this lane's 4 spheres of link l into padded LDS
    #pragma unroll
    for (int k = 0; k < 4; ++k) {
        const int sp = g * 4 + k;
        float4 cs = reinterpret_cast<const float4*>(spheres)[l*8 + sp];
        float wx = fmaf(R00,cs.x, fmaf(R01,cs.y, fmaf(R02,cs.z, t0)));
        float wy = fmaf(R10,cs.x, fmaf(R11,cs.y, fmaf(R12,cs.z, t1)));
        float wz = fmaf(R20,cs.x, fmaf(R21,cs.y, fmaf(R22,cs.z, t2)));
        sph[w][h][l*9 + sp] = make_float4(wx, wy, wz, cs.w);
    }
    // wave-private LDS region: just drain this wave's writes, no barrier
    asm volatile("s_waitcnt lgkmcnt(0)" ::: "memory");

    // ---- pairwise penetration, per-link max (32 lanes per batch)
    const float4* S  = sph[w][h];
    const float*  Sf = reinterpret_cast<const float*>(S);
    const int L   = lane & 31;
    const int sr  = L >> 2;        // row sphere 0..7
    const int sc2 = L & 3;         // column spheres {sc2, sc2+4}

    float m[16];
    #pragma unroll
    for (int k = 0; k < 16; ++k) m[k] = -100.0f;

    // column cache fill: paired scalar LDS loads (-> ds_read2_b32), born packed
    #define FILL_CS(jj, j)                                                      \
    {                                                                           \
        const int bd = (j)*36 + sc2*4;                                          \
        cx[jj] = (v2f){Sf[bd+0], Sf[bd+16]};                                    \
        cy[jj] = (v2f){Sf[bd+1], Sf[bd+17]};                                    \
        cz[jj] = (v2f){Sf[bd+2], Sf[bd+18]};                                    \
        cw[jj] = (v2f){Sf[bd+3], Sf[bd+19]};                                    \
    }

    // ---- Pass A: columns j in [2,8], rows i in [0,6]
    {
        v2f cx[7], cy[7], cz[7], cw[7];
        #pragma unroll
        for (int j = 2; j <= 8; ++j) FILL_CS(j-2, j)

        #pragma unroll
        for (int i = 0; i <= 6; ++i) {
            float4 rs = S[i*9 + sr];
            #pragma unroll
            for (int j = i + 2; j <= 8; ++j)
                pen2p(rs, cx[j-2], cy[j-2], cz[j-2], cw[j-2], m[i], m[j]);
        }
    }
    // ---- Pass B: columns j in [9,15], rows i in [0,13]
    {
        v2f cx[7], cy[7], cz[7], cw[7];
        #pragma unroll
        for (int j = 9; j <= 15; ++j) FILL_CS(j-9, j)

        #pragma unroll
        for (int i = 0; i <= 13; ++i) {
            float4 rs = S[i*9 + sr];
            const int j0 = (i + 2 > 9) ? (i + 2) : 9;
            #pragma unroll
            for (int j = 9; j <= 15; ++j) {
                if (j < j0) continue;
                pen2p(rs, cx[j-9], cy[j-9], cz[j-9], cw[j-9], m[i], m[j]);
            }
        }
    }
    #undef FILL_CS

    // ---- log-fold reduction over the 32 lanes of this batch half
    {
        int bit0 = lane & 1;
        #pragma unroll
        for (int k = 0; k < 8; ++k) {
            float send = bit0 ? m[k] : m[k+8];
            float recv = dppmov<DPP_XOR1>(send);
            m[k] = fmaxf(bit0 ? m[k+8] : m[k], recv);
        }
        int bit1 = (lane >> 1) & 1;
        #pragma unroll
        for (int k = 0; k < 4; ++k) {
            float send = bit1 ? m[k] : m[k+4];
            float recv = dppmov<DPP_XOR2>(send);
            m[k] = fmaxf(bit1 ? m[k+4] : m[k], recv);
        }
        int bit2 = (lane >> 2) & 1;
        #pragma unroll
        for (int k = 0; k < 2; ++k) {
            float send = bit2 ? m[k] : m[k+2];
            float recv = __shfl_xor(send, 4, 64);
            m[k] = fmaxf(bit2 ? m[k+2] : m[k], recv);
        }
        int bit3 = (lane >> 3) & 1;
        {
            float send = bit3 ? m[0] : m[1];
            float recv = dppmov<DPP_XOR8>(send);
            m[0] = fmaxf(bit3 ? m[1] : m[0], recv);
        }
        // merge the two 16-lane groups of this batch half
        float v = m[0];
        v = fmaxf(v, __shfl_xor(v, 16, 64));
        m[0] = v;
    }

    if (alive && (lane & 16) == 0) {
        // link index = bit-reversal of lane's low 4 bits
        int k = ((lane & 1) << 3) | ((lane & 2) << 1) | ((lane & 4) >> 1) | ((lane & 8) >> 3);
        out[(size_t)b * 16 + k] = m[0];
    }
}

// ---------------------------------------------------------------------------
extern "C" void kernel_launch(void* const* d_in, const int* in_sizes, int n_in,
                              void* d_out, int out_size, void* d_ws, size_t ws_size,
                              hipStream_t stream) {
    const float* q      = (const float*)d_in[0];
    const float* frot   = (const float*)d_in[1];
    const float* ftrans = (const float*)d_in[2];
    const float* axes   = (const float*)d_in[3];
    const float* sphere = (const float*)d_in[4];
    float* out = (float*)d_out;

    const int B = in_sizes[0] / 16;
    const int blocks = (B + 7) / 8;     // 2 batches per wave, 8 per block
    fused_kernel<<<dim3(blocks), dim3(256), 0, stream>>>(
        q, frot, ftrans, axes, sphere, out, B);
}